// Round 6
// baseline (389.356 us; speedup 1.0000x reference)
//
#include <hip/hip_runtime.h>
#include <cstdint>
#include <cstddef>

#define EPSV 1e-5f

using f32x4  = __attribute__((ext_vector_type(4))) float;
using bf16x8 = __attribute__((ext_vector_type(8))) short;

// RNE pack of two f32 into two bf16 (lo -> low16, hi -> high16)
static __device__ __forceinline__ unsigned pk2(float lo, float hi) {
    unsigned a = __builtin_bit_cast(unsigned, lo);
    unsigned b = __builtin_bit_cast(unsigned, hi);
    a = (a + 0x7FFFu + ((a >> 16) & 1u)) >> 16;
    b = (b + 0x7FFFu + ((b >> 16) & 1u)) & 0xFFFF0000u;
    return a | b;
}

// pack 8 k-consecutive f32 (two float4) into bf16x8
static __device__ __forceinline__ bf16x8 pk8(float4 lo, float4 hi) {
    uint4 u = make_uint4(pk2(lo.x, lo.y), pk2(lo.z, lo.w),
                         pk2(hi.x, hi.y), pk2(hi.z, hi.w));
    return __builtin_bit_cast(bf16x8, u);
}

// ---------------------------------------------------------------------------
__global__ __launch_bounds__(256) void prep_params(
    const float* __restrict__ rwb, const float* __restrict__ rg,
    const float* __restrict__ rb,  const float* __restrict__ rm,
    const float* __restrict__ rv,
    const float* __restrict__ ewb, const float* __restrict__ eg,
    const float* __restrict__ eb,  const float* __restrict__ em,
    const float* __restrict__ ev,
    const float* __restrict__ bg,  const float* __restrict__ bb,
    const float* __restrict__ bm,  const float* __restrict__ bv,
    float* __restrict__ prm)
{
    int t = threadIdx.x;
    if (t < 128) {
        float sc = rg[t] * rsqrtf(rv[t] + EPSV);
        prm[t]       = sc;
        prm[128 + t] = rb[t] - rm[t] * sc + rwb[t] * sc;
        float bsc = bg[t] * rsqrtf(bv[t] + EPSV);
        prm[768 + t] = bsc;
        prm[896 + t] = bb[t] - bm[t] * bsc;
    }
    {
        float sc = eg[t] * rsqrtf(ev[t] + EPSV);
        prm[256 + t] = sc;
        prm[512 + t] = eb[t] - em[t] * sc + ewb[t] * sc;
    }
}

// ---------------------------------------------------------------------------
// LDS-free, barrier-free bf16 MFMA GEMM + BN + (residual) + ReLU.
// In [NB][Cin][P] f32, Wt [O][Cin] f32, Out [NB][O][P] f32.
// 256 thr = 4 INDEPENDENT waves (2x2); wave tile 64(o) x 32(p); BK=32.
// Per-lane fragments loaded directly from global (A: 2 x dwordx4,
// B: 8 x dword, 64B-segment coalesced over 16-lane groups), converted
// in-register. 2-stage software pipeline over K. Requires P%64==0, Cin%64==0.
// D decode (m89): col=lane&15, row=(lane>>4)*4+r.
// ---------------------------------------------------------------------------
struct Stage {
    float4 a[4][2];
    float  b[2][8];
};

__global__ __launch_bounds__(256) void gemm_direct(
    const float* __restrict__ In,
    const float* __restrict__ Wt,
    const float* __restrict__ scale,
    const float* __restrict__ shift,
    const float* __restrict__ resid,
    float* __restrict__ Out,
    int Cin, int O, int P)
{
    const int n    = blockIdx.z;
    const int p0   = blockIdx.x * 64;
    const int o0   = blockIdx.y * 128;
    const int tid  = threadIdx.x;
    const int lane = tid & 63;
    const int wid  = tid >> 6;
    const int wm   = wid >> 1, wn = wid & 1;

    const int rl = lane & 15;
    const int k0 = (lane >> 4) * 8;

    const float* __restrict__ inn = In + (size_t)n * Cin * P;

    // per-lane base pointers
    const float* ap[4];
    #pragma unroll
    for (int i = 0; i < 4; ++i)
        ap[i] = Wt + (size_t)(o0 + wm * 64 + i * 16 + rl) * Cin + k0;
    const float* bp[2];
    #pragma unroll
    for (int j = 0; j < 2; ++j)
        bp[j] = inn + (size_t)k0 * P + (p0 + wn * 32 + j * 16 + rl);

    f32x4 acc[4][2];
    #pragma unroll
    for (int i = 0; i < 4; ++i)
        #pragma unroll
        for (int j = 0; j < 2; ++j) acc[i][j] = (f32x4)0.f;

    Stage s0, s1;

    auto load = [&](Stage& s, int kc) {
        #pragma unroll
        for (int i = 0; i < 4; ++i) {
            s.a[i][0] = *(const float4*)(ap[i] + kc);
            s.a[i][1] = *(const float4*)(ap[i] + kc + 4);
        }
        #pragma unroll
        for (int j = 0; j < 2; ++j)
            #pragma unroll
            for (int kk = 0; kk < 8; ++kk)
                s.b[j][kk] = bp[j][(size_t)(kc + kk) * P];
    };

    auto compute = [&](const Stage& s) {
        bf16x8 af[4], bf[2];
        #pragma unroll
        for (int i = 0; i < 4; ++i)
            af[i] = pk8(s.a[i][0], s.a[i][1]);
        #pragma unroll
        for (int j = 0; j < 2; ++j) {
            bf[j] = pk8(make_float4(s.b[j][0], s.b[j][1], s.b[j][2], s.b[j][3]),
                        make_float4(s.b[j][4], s.b[j][5], s.b[j][6], s.b[j][7]));
        }
        #pragma unroll
        for (int i = 0; i < 4; ++i)
            #pragma unroll
            for (int j = 0; j < 2; ++j)
                acc[i][j] = __builtin_amdgcn_mfma_f32_16x16x32_bf16(
                    af[i], bf[j], acc[i][j], 0, 0, 0);
    };

    // 2-step software pipeline (Cin % 64 == 0 -> even step count)
    load(s0, 0);
    for (int kc = 0; kc < Cin; kc += 64) {
        load(s1, kc + 32);
        compute(s0);
        if (kc + 64 < Cin) load(s0, kc + 64);
        compute(s1);
    }

    // epilogue: BN + residual + ReLU
    #pragma unroll
    for (int i = 0; i < 4; ++i) {
        #pragma unroll
        for (int r = 0; r < 4; ++r) {
            int o = o0 + wm * 64 + i * 16 + (lane >> 4) * 4 + r;
            float sc = scale[o], sh = shift[o];
            size_t base = ((size_t)n * O + o) * P;
            #pragma unroll
            for (int j = 0; j < 2; ++j) {
                int p = p0 + wn * 32 + j * 16 + rl;
                float v = fmaf(acc[i][j][r], sc, sh);
                if (resid) v += resid[base + p];
                Out[base + p] = fmaxf(v, 0.f);
            }
        }
    }
}

// ---------------------------------------------------------------------------
// res2net branch step (unchanged, verified)
// ---------------------------------------------------------------------------
__global__ __launch_bounds__(256) void gcn_step(
    const float* __restrict__ h,
    float* __restrict__ outs,
    const float* __restrict__ gw,
    const float* __restrict__ gb,
    const float* __restrict__ Aadj,
    const float* __restrict__ PAi,
    const float* __restrict__ bscale,
    const float* __restrict__ bshift,
    int step)
{
    const int n  = blockIdx.y;
    const int tt = blockIdx.x;
    const int tid = threadIdx.x;
    const int c  = tid & 31;
    const int tl = tid >> 5;

    __shared__ float sp[32 * 200];
    __shared__ float wsg[96][33];
    __shared__ float Mm[3][25][28];

    const size_t pbase = (size_t)tt * 200;
    const float* hch = h + ((size_t)n * 128 + (size_t)step * 32) * 1600 + pbase;
    const float* pch = (step > 0)
        ? outs + ((size_t)n * 128 + (size_t)(step - 1) * 32) * 1600 + pbase
        : nullptr;

    for (int idx = tid; idx < 32 * 200; idx += 256) {
        int cin = idx / 200, pp = idx % 200;
        float v = hch[(size_t)cin * 1600 + pp];
        if (pch) v += pch[(size_t)cin * 1600 + pp];
        sp[idx] = v;
    }
    for (int idx = tid; idx < 96 * 32; idx += 256)
        wsg[idx >> 5][idx & 31] = gw[idx];
    for (int idx = tid; idx < 3 * 625; idx += 256) {
        int k = idx / 625, rem = idx % 625;
        Mm[k][rem / 25][rem % 25] = Aadj[idx] + PAi[idx];
    }
    __syncthreads();

    float g[3][25];
    {
        float b0 = gb[c], b1 = gb[32 + c], b2 = gb[64 + c];
        #pragma unroll
        for (int v = 0; v < 25; ++v) { g[0][v] = b0; g[1][v] = b1; g[2][v] = b2; }
    }
    for (int cin = 0; cin < 32; ++cin) {
        float w0 = wsg[c][cin], w1 = wsg[32 + c][cin], w2 = wsg[64 + c][cin];
        const float* s = &sp[cin * 200 + tl * 25];
        #pragma unroll
        for (int v = 0; v < 25; ++v) {
            float sv = s[v];
            g[0][v] = fmaf(w0, sv, g[0][v]);
            g[1][v] = fmaf(w1, sv, g[1][v]);
            g[2][v] = fmaf(w2, sv, g[2][v]);
        }
    }

    float out[25];
    #pragma unroll
    for (int w = 0; w < 25; ++w) out[w] = 0.f;
    #pragma unroll
    for (int k = 0; k < 3; ++k)
        #pragma unroll
        for (int v = 0; v < 25; ++v) {
            float gv = g[k][v];
            #pragma unroll
            for (int w = 0; w < 25; ++w)
                out[w] = fmaf(gv, Mm[k][v][w], out[w]);
        }

    float sc = bscale[c], sh = bshift[c];
    __syncthreads();
    #pragma unroll
    for (int w = 0; w < 25; ++w)
        sp[c * 200 + tl * 25 + w] = fmaxf(fmaf(out[w], sc, sh), 0.f);
    __syncthreads();

    float* och = outs + ((size_t)n * 128 + (size_t)step * 32) * 1600 + pbase;
    for (int idx = tid; idx < 32 * 200; idx += 256)
        och[(size_t)(idx / 200) * 1600 + (idx % 200)] = sp[idx];
}

// ---------------------------------------------------------------------------
extern "C" void kernel_launch(void* const* d_in, const int* in_sizes, int n_in,
                              void* d_out, int out_size, void* d_ws, size_t ws_size,
                              hipStream_t stream)
{
    const float* x   = (const float*)d_in[0];
    const float* A   = (const float*)d_in[1];
    const float* rw  = (const float*)d_in[2];
    const float* rwb = (const float*)d_in[3];
    const float* rg  = (const float*)d_in[4];
    const float* rb  = (const float*)d_in[5];
    const float* rm  = (const float*)d_in[6];
    const float* rv  = (const float*)d_in[7];
    const float* gw  = (const float*)d_in[8];
    const float* gb  = (const float*)d_in[9];
    const float* PA  = (const float*)d_in[10];
    const float* bg  = (const float*)d_in[11];
    const float* bb  = (const float*)d_in[12];
    const float* bm  = (const float*)d_in[13];
    const float* bv  = (const float*)d_in[14];
    const float* ew  = (const float*)d_in[15];
    const float* ewb = (const float*)d_in[16];
    const float* eg  = (const float*)d_in[17];
    const float* eb  = (const float*)d_in[18];
    const float* em  = (const float*)d_in[19];
    const float* ev  = (const float*)d_in[20];

    float* wsf  = (float*)d_ws;
    float* h    = wsf;                    // 13,107,200 floats
    float* outs = wsf + 13107200;         // 13,107,200 floats
    float* prm  = wsf + 26214400;         // 1024 floats

    prep_params<<<1, 256, 0, stream>>>(rwb, rg, rb, rm, rv,
                                       ewb, eg, eb, em, ev,
                                       bg, bb, bm, bv, prm);

    // reduct: x[64][256][1600] -> h[64][128][1600]
    gemm_direct<<<dim3(25, 1, 64), 256, 0, stream>>>(
        x, rw, prm, prm + 128, nullptr, h, 256, 128, 1600);

    for (int i = 0; i < 4; ++i) {
        gcn_step<<<dim3(8, 64), 256, 0, stream>>>(
            h, outs, gw + (size_t)i * 96 * 32, gb + (size_t)i * 96,
            A, PA + (size_t)i * 3 * 625,
            prm + 768 + i * 32, prm + 896 + i * 32, i);
    }

    // expand: outs -> d_out (+x residual)
    gemm_direct<<<dim3(25, 2, 64), 256, 0, stream>>>(
        outs, ew, prm + 256, prm + 512, x, (float*)d_out, 128, 256, 1600);
}

// Round 7
// 288.082 us; speedup vs baseline: 1.3515x; 1.3515x over previous
//
#include <hip/hip_runtime.h>
#include <cstdint>
#include <cstddef>

#define EPSV 1e-5f

using f32x4  = __attribute__((ext_vector_type(4))) float;
using bf16x8 = __attribute__((ext_vector_type(8))) short;

// RNE pack of two f32 into two bf16 (lo -> low16, hi -> high16)
static __device__ __forceinline__ unsigned pk2(float lo, float hi) {
    unsigned a = __builtin_bit_cast(unsigned, lo);
    unsigned b = __builtin_bit_cast(unsigned, hi);
    a = (a + 0x7FFFu + ((a >> 16) & 1u)) >> 16;
    b = (b + 0x7FFFu + ((b >> 16) & 1u)) & 0xFFFF0000u;
    return a | b;
}
static __device__ __forceinline__ unsigned short bf16of(float v) {
    return (unsigned short)(pk2(v, 0.f) & 0xFFFFu);
}
// unpack uint -> two f32 (lo16 = first elem)
static __device__ __forceinline__ void unpk2(unsigned u, float& lo, float& hi) {
    lo = __builtin_bit_cast(float, u << 16);
    hi = __builtin_bit_cast(float, u & 0xFFFF0000u);
}

// LDS index swizzle (round-5 verified): rows of 32 shorts.
static __device__ __forceinline__ int sidx(int row, int k) {
    return (row * 32 + k) ^ (((row >> 1) & 7) << 3);
}

// ---------------------------------------------------------------------------
__global__ __launch_bounds__(256) void prep_params(
    const float* __restrict__ rwb, const float* __restrict__ rg,
    const float* __restrict__ rb,  const float* __restrict__ rm,
    const float* __restrict__ rv,
    const float* __restrict__ ewb, const float* __restrict__ eg,
    const float* __restrict__ eb,  const float* __restrict__ em,
    const float* __restrict__ ev,
    const float* __restrict__ bg,  const float* __restrict__ bb,
    const float* __restrict__ bm,  const float* __restrict__ bv,
    float* __restrict__ prm)
{
    int t = threadIdx.x;
    if (t < 128) {
        float sc = rg[t] * rsqrtf(rv[t] + EPSV);
        prm[t]       = sc;
        prm[128 + t] = rb[t] - rm[t] * sc + rwb[t] * sc;
        float bsc = bg[t] * rsqrtf(bv[t] + EPSV);
        prm[768 + t] = bsc;
        prm[896 + t] = bb[t] - bm[t] * bsc;
    }
    {
        float sc = eg[t] * rsqrtf(ev[t] + EPSV);
        prm[256 + t] = sc;
        prm[512 + t] = eb[t] - em[t] * sc + ewb[t] * sc;
    }
}

// ---------------------------------------------------------------------------
// x [64][256][1600] f32  ->  xT [64][1600][256] bf16   (LDS-tiled transpose)
// ---------------------------------------------------------------------------
__global__ __launch_bounds__(256) void xpose(
    const float* __restrict__ x, unsigned short* __restrict__ xT)
{
    const int n  = blockIdx.z;
    const int cb = blockIdx.y * 64;
    const int pb = blockIdx.x * 64;
    __shared__ float tile[64][65];

    const float* xin = x + ((size_t)n * 256 + cb) * 1600 + pb;
    #pragma unroll
    for (int it = 0; it < 4; ++it) {
        int idx = threadIdx.x + it * 256;
        int cl = idx >> 4, p4 = (idx & 15) << 2;
        float4 v = *(const float4*)(xin + (size_t)cl * 1600 + p4);
        tile[cl][p4] = v.x; tile[cl][p4 + 1] = v.y;
        tile[cl][p4 + 2] = v.z; tile[cl][p4 + 3] = v.w;
    }
    __syncthreads();
    #pragma unroll
    for (int it = 0; it < 2; ++it) {
        int idx = threadIdx.x + it * 256;
        int p = idx >> 3, c8 = (idx & 7) << 3;
        float f[8];
        #pragma unroll
        for (int q = 0; q < 8; ++q) f[q] = tile[c8 + q][p];
        uint4 u = make_uint4(pk2(f[0], f[1]), pk2(f[2], f[3]),
                             pk2(f[4], f[5]), pk2(f[6], f[7]));
        *(uint4*)(xT + ((size_t)n * 1600 + pb + p) * 256 + cb + c8) = u;
    }
}

// ---------------------------------------------------------------------------
// bf16 MFMA GEMM: BT [NB][P][Cin] bf16, Wt [O][Cin] f32.
// BF16OUT: Out = bf16 [NB][P][O] (via LDS transpose);
// else:    Out = f32  [NB][O][P] with +resid, ReLU.
// Round-5 verified pipeline/fragments; B staging = 1 uint4 + 1 b128 write.
// ---------------------------------------------------------------------------
template<bool BF16OUT>
__global__ __launch_bounds__(256) void gemm_bf16(
    const unsigned short* __restrict__ BT,
    const float* __restrict__ Wt,
    const float* __restrict__ scale,
    const float* __restrict__ shift,
    const float* __restrict__ resid,
    void* __restrict__ OutP,
    int Cin, int O, int P)
{
    const int n    = blockIdx.z;
    const int p0   = blockIdx.x * 64;
    const int o0   = blockIdx.y * 128;
    const int tid  = threadIdx.x;
    const int lane = tid & 63;
    const int wid  = tid >> 6;
    const int wm   = wid >> 1, wn = wid & 1;
    const int rl   = lane & 15;

    __shared__ short sA[2][128 * 32];
    __shared__ short sB[2][64 * 32];

    const int ao = tid >> 1;
    const int ak = (tid & 1) * 16;
    const int bp = tid & 63;
    const int kb = (tid >> 6) << 3;
    const unsigned short* brow = BT + ((size_t)n * P + p0 + bp) * Cin + kb;

    float4 ra[4];
    uint4  bu;

    f32x4 acc[4][2];
    #pragma unroll
    for (int i = 0; i < 4; ++i)
        #pragma unroll
        for (int j = 0; j < 2; ++j) acc[i][j] = (f32x4)0.f;

    const int nt = Cin >> 5;

    auto load_regs = [&](int kc) {
        const float* wrow = Wt + (size_t)(o0 + ao) * Cin + kc + ak;
        #pragma unroll
        for (int i = 0; i < 4; ++i)
            ra[i] = *(const float4*)(wrow + i * 4);
        bu = *(const uint4*)(brow + kc);
    };

    auto write_lds = [&](int buf) {
        uint4 w0 = make_uint4(pk2(ra[0].x, ra[0].y), pk2(ra[0].z, ra[0].w),
                              pk2(ra[1].x, ra[1].y), pk2(ra[1].z, ra[1].w));
        uint4 w1 = make_uint4(pk2(ra[2].x, ra[2].y), pk2(ra[2].z, ra[2].w),
                              pk2(ra[3].x, ra[3].y), pk2(ra[3].z, ra[3].w));
        *(uint4*)(&sA[buf][sidx(ao, ak)])     = w0;
        *(uint4*)(&sA[buf][sidx(ao, ak + 8)]) = w1;
        *(uint4*)(&sB[buf][sidx(bp, kb)])     = bu;
    };

    auto compute = [&](int buf) {
        const int k0 = (lane >> 4) * 8;
        bf16x8 af[4], bfr[2];
        #pragma unroll
        for (int i = 0; i < 4; ++i)
            af[i]  = *(const bf16x8*)(&sA[buf][sidx(wm * 64 + i * 16 + rl, k0)]);
        #pragma unroll
        for (int j = 0; j < 2; ++j)
            bfr[j] = *(const bf16x8*)(&sB[buf][sidx(wn * 32 + j * 16 + rl, k0)]);
        #pragma unroll
        for (int i = 0; i < 4; ++i)
            #pragma unroll
            for (int j = 0; j < 2; ++j)
                acc[i][j] = __builtin_amdgcn_mfma_f32_16x16x32_bf16(
                    af[i], bfr[j], acc[i][j], 0, 0, 0);
    };

    load_regs(0);
    write_lds(0);
    for (int t = 0; t < nt; ++t) {
        if (t + 1 < nt) load_regs((t + 1) << 5);
        __syncthreads();
        compute(t & 1);
        if (t + 1 < nt) write_lds((t + 1) & 1);
    }

    if constexpr (BF16OUT) {
        // transpose epilogue -> [p][o] bf16, XOR-swizzled staging in sA space
        __syncthreads();
        unsigned short* eL = (unsigned short*)&sA[0][0];   // 64p x O shorts
        #pragma unroll
        for (int i = 0; i < 4; ++i) {
            #pragma unroll
            for (int r = 0; r < 4; ++r) {
                int o = o0 + wm * 64 + i * 16 + (lane >> 4) * 4 + r;
                float sc = scale[o], sh = shift[o];
                int ol = o - o0;
                #pragma unroll
                for (int j = 0; j < 2; ++j) {
                    int p = wn * 32 + j * 16 + rl;
                    float v = fmaxf(fmaf(acc[i][j][r], sc, sh), 0.f);
                    eL[p * 128 + (ol ^ ((p & 15) << 3))] = bf16of(v);
                }
            }
        }
        __syncthreads();
        unsigned short* out = (unsigned short*)OutP;
        #pragma unroll
        for (int it = 0; it < 4; ++it) {
            int idx = tid + it * 256;          // 1024 uint4 = 64p x 16
            int p = idx >> 4, m = idx & 15;
            uint4 u = *(const uint4*)(&eL[p * 128 + ((m ^ (p & 15)) << 3)]);
            *(uint4*)(out + ((size_t)n * P + p0 + p) * O + (m << 3)) = u;
        }
    } else {
        float* out = (float*)OutP;
        #pragma unroll
        for (int i = 0; i < 4; ++i) {
            #pragma unroll
            for (int r = 0; r < 4; ++r) {
                int o = o0 + wm * 64 + i * 16 + (lane >> 4) * 4 + r;
                float sc = scale[o], sh = shift[o];
                size_t base = ((size_t)n * O + o) * P;
                #pragma unroll
                for (int j = 0; j < 2; ++j) {
                    int p = p0 + wn * 32 + j * 16 + rl;
                    float v = fmaf(acc[i][j][r], sc, sh);
                    if (resid) v += resid[base + p];
                    out[base + p] = fmaxf(v, 0.f);
                }
            }
        }
    }
}

// ---------------------------------------------------------------------------
// res2net branch step, bf16 [p][c] I/O.
// hT/outsT: [64][1600][128] bf16. Per block: n, 200-p tile.
// ---------------------------------------------------------------------------
__global__ __launch_bounds__(256) void gcn_step(
    const unsigned short* __restrict__ hT,
    unsigned short* __restrict__ outsT,
    const float* __restrict__ gw,     // [96][32]
    const float* __restrict__ gb,     // [96]
    const float* __restrict__ Aadj,   // [3][25][25]
    const float* __restrict__ PAi,    // [3][25][25]
    const float* __restrict__ bscale, // [32]
    const float* __restrict__ bshift, // [32]
    int step)
{
    const int n  = blockIdx.y;
    const int tt = blockIdx.x;
    const int tid = threadIdx.x;
    const int c  = tid & 31;
    const int tl = tid >> 5;

    __shared__ float smem[7200 + 3168 + 2100];
    float* sp  = smem;                          // [200][36]
    float* wsg = smem + 7200;                   // [96][33]
    float (*Mm)[25][28] = (float(*)[25][28])(smem + 7200 + 3168);
    unsigned short* outb = (unsigned short*)(smem + 7200);  // [200][32] alias

    const size_t rowbase = (size_t)n * 1600 + (size_t)tt * 200;
    const unsigned short* hrow = hT + rowbase * 128 + step * 32;
    const unsigned short* prow = outsT + rowbase * 128 + (step - 1) * 32;

    for (int idx = tid; idx < 800; idx += 256) {
        int p = idx >> 2, c8 = (idx & 3) << 3;
        uint4 u = *(const uint4*)(hrow + (size_t)p * 128 + c8);
        float f[8];
        unpk2(u.x, f[0], f[1]); unpk2(u.y, f[2], f[3]);
        unpk2(u.z, f[4], f[5]); unpk2(u.w, f[6], f[7]);
        if (step > 0) {
            uint4 v = *(const uint4*)(prow + (size_t)p * 128 + c8);
            float g0, g1;
            unpk2(v.x, g0, g1); f[0] += g0; f[1] += g1;
            unpk2(v.y, g0, g1); f[2] += g0; f[3] += g1;
            unpk2(v.z, g0, g1); f[4] += g0; f[5] += g1;
            unpk2(v.w, g0, g1); f[6] += g0; f[7] += g1;
        }
        float* d = sp + p * 36 + c8;
        *(float4*)d       = make_float4(f[0], f[1], f[2], f[3]);
        *(float4*)(d + 4) = make_float4(f[4], f[5], f[6], f[7]);
    }
    for (int idx = tid; idx < 96 * 32; idx += 256)
        wsg[(idx >> 5) * 33 + (idx & 31)] = gw[idx];
    for (int idx = tid; idx < 3 * 625; idx += 256) {
        int k = idx / 625, rem = idx % 625;
        Mm[k][rem / 25][rem % 25] = Aadj[idx] + PAi[idx];
    }
    __syncthreads();

    // phase 1: conv 32->96 into registers (sp reads are wave-broadcast)
    float g[3][25];
    {
        float b0 = gb[c], b1 = gb[32 + c], b2 = gb[64 + c];
        #pragma unroll
        for (int v = 0; v < 25; ++v) { g[0][v] = b0; g[1][v] = b1; g[2][v] = b2; }
    }
    const float* srow = sp + tl * 25 * 36;
    for (int cin = 0; cin < 32; ++cin) {
        float w0 = wsg[c * 33 + cin];
        float w1 = wsg[(32 + c) * 33 + cin];
        float w2 = wsg[(64 + c) * 33 + cin];
        #pragma unroll
        for (int v = 0; v < 25; ++v) {
            float sv = srow[v * 36 + cin];
            g[0][v] = fmaf(w0, sv, g[0][v]);
            g[1][v] = fmaf(w1, sv, g[1][v]);
            g[2][v] = fmaf(w2, sv, g[2][v]);
        }
    }

    // phase 2: adjacency mix
    float out[25];
    #pragma unroll
    for (int w = 0; w < 25; ++w) out[w] = 0.f;
    #pragma unroll
    for (int k = 0; k < 3; ++k)
        #pragma unroll
        for (int v = 0; v < 25; ++v) {
            float gv = g[k][v];
            #pragma unroll
            for (int w = 0; w < 25; ++w)
                out[w] = fmaf(gv, Mm[k][v][w], out[w]);
        }

    // phase 3: BN + ReLU -> bf16, restage -> coalesced [p][c] store
    float sc = bscale[c], sh = bshift[c];
    __syncthreads();                      // wsg/Mm reads done; outb aliases
    #pragma unroll
    for (int w = 0; w < 25; ++w)
        outb[(tl * 25 + w) * 32 + c] = bf16of(fmaxf(fmaf(out[w], sc, sh), 0.f));
    __syncthreads();

    unsigned short* orow = outsT + rowbase * 128 + step * 32;
    for (int idx = tid; idx < 800; idx += 256) {
        int p = idx >> 2, c8 = (idx & 3) << 3;
        uint4 u = *(const uint4*)(&outb[p * 32 + c8]);
        *(uint4*)(orow + (size_t)p * 128 + c8) = u;
    }
}

// ---------------------------------------------------------------------------
extern "C" void kernel_launch(void* const* d_in, const int* in_sizes, int n_in,
                              void* d_out, int out_size, void* d_ws, size_t ws_size,
                              hipStream_t stream)
{
    const float* x   = (const float*)d_in[0];
    const float* A   = (const float*)d_in[1];
    const float* rw  = (const float*)d_in[2];
    const float* rwb = (const float*)d_in[3];
    const float* rg  = (const float*)d_in[4];
    const float* rb  = (const float*)d_in[5];
    const float* rm  = (const float*)d_in[6];
    const float* rv  = (const float*)d_in[7];
    const float* gw  = (const float*)d_in[8];
    const float* gb  = (const float*)d_in[9];
    const float* PA  = (const float*)d_in[10];
    const float* bg  = (const float*)d_in[11];
    const float* bb  = (const float*)d_in[12];
    const float* bm  = (const float*)d_in[13];
    const float* bv  = (const float*)d_in[14];
    const float* ew  = (const float*)d_in[15];
    const float* ewb = (const float*)d_in[16];
    const float* eg  = (const float*)d_in[17];
    const float* eb  = (const float*)d_in[18];
    const float* em  = (const float*)d_in[19];
    const float* ev  = (const float*)d_in[20];

    char* wsb = (char*)d_ws;
    unsigned short* hT    = (unsigned short*)wsb;               // 26,214,400 B
    unsigned short* outsT = (unsigned short*)(wsb + 26214400);  // 26,214,400 B
    unsigned short* xT    = (unsigned short*)(wsb + 52428800);  // 52,428,800 B
    float*          prm   = (float*)(wsb + 104857600);          // 4 KB

    prep_params<<<1, 256, 0, stream>>>(rwb, rg, rb, rm, rv,
                                       ewb, eg, eb, em, ev,
                                       bg, bb, bm, bv, prm);

    // x -> xT bf16 [n][p][c]
    xpose<<<dim3(25, 4, 64), 256, 0, stream>>>(x, xT);

    // reduct: xT -> hT bf16 [n][p][128]
    gemm_bf16<true><<<dim3(25, 1, 64), 256, 0, stream>>>(
        xT, rw, prm, prm + 128, nullptr, hT, 256, 128, 1600);

    for (int i = 0; i < 4; ++i) {
        gcn_step<<<dim3(8, 64), 256, 0, stream>>>(
            hT, outsT, gw + (size_t)i * 96 * 32, gb + (size_t)i * 96,
            A, PA + (size_t)i * 3 * 625,
            prm + 768 + i * 32, prm + 896 + i * 32, i);
    }

    // expand: outsT -> d_out f32 [n][256][1600] (+x residual)
    gemm_bf16<false><<<dim3(25, 2, 64), 256, 0, stream>>>(
        outsT, ew, prm + 256, prm + 512, x, d_out, 128, 256, 1600);
}

// Round 8
// 275.718 us; speedup vs baseline: 1.4122x; 1.0448x over previous
//
#include <hip/hip_runtime.h>
#include <cstdint>
#include <cstddef>

#define EPSV 1e-5f

using f32x4  = __attribute__((ext_vector_type(4))) float;
using bf16x8 = __attribute__((ext_vector_type(8))) short;

// RNE pack of two f32 into two bf16 (lo -> low16, hi -> high16)
static __device__ __forceinline__ unsigned pk2(float lo, float hi) {
    unsigned a = __builtin_bit_cast(unsigned, lo);
    unsigned b = __builtin_bit_cast(unsigned, hi);
    a = (a + 0x7FFFu + ((a >> 16) & 1u)) >> 16;
    b = (b + 0x7FFFu + ((b >> 16) & 1u)) & 0xFFFF0000u;
    return a | b;
}
static __device__ __forceinline__ unsigned short bf16of(float v) {
    return (unsigned short)(pk2(v, 0.f) & 0xFFFFu);
}
static __device__ __forceinline__ void unpk2(unsigned u, float& lo, float& hi) {
    lo = __builtin_bit_cast(float, u << 16);
    hi = __builtin_bit_cast(float, u & 0xFFFF0000u);
}

// 128-short-row LDS swizzle, 8-short (16 B) granule. All 16 B accesses use
// k % 8 == 0 so the XOR'd granule stays intact (bijective per row).
static __device__ __forceinline__ int S128(int row, int k) {
    return (row * 128 + k) ^ ((row & 15) << 3);
}

// ---------------------------------------------------------------------------
__global__ __launch_bounds__(256) void prep_params(
    const float* __restrict__ rwb, const float* __restrict__ rg,
    const float* __restrict__ rb,  const float* __restrict__ rm,
    const float* __restrict__ rv,
    const float* __restrict__ ewb, const float* __restrict__ eg,
    const float* __restrict__ eb,  const float* __restrict__ em,
    const float* __restrict__ ev,
    const float* __restrict__ bg,  const float* __restrict__ bb,
    const float* __restrict__ bm,  const float* __restrict__ bv,
    float* __restrict__ prm)
{
    int t = threadIdx.x;
    if (t < 128) {
        float sc = rg[t] * rsqrtf(rv[t] + EPSV);
        prm[t]       = sc;
        prm[128 + t] = rb[t] - rm[t] * sc + rwb[t] * sc;
        float bsc = bg[t] * rsqrtf(bv[t] + EPSV);
        prm[768 + t] = bsc;
        prm[896 + t] = bb[t] - bm[t] * bsc;
    }
    {
        float sc = eg[t] * rsqrtf(ev[t] + EPSV);
        prm[256 + t] = sc;
        prm[512 + t] = eb[t] - em[t] * sc + ewb[t] * sc;
    }
}

// ---------------------------------------------------------------------------
// Chunk-GEMM: BK=128, single-buffered LDS, 2 barriers per chunk.
// A = Wt [O][Cin] f32. B: B_F32 ? f32 [NB][Cin][P] : bf16 [NB][P][Cin].
// BF16OUT: Out = bf16 [NB][P][O] (O==128) via LDS-transposed epilogue;
// else:    Out = f32 [NB][O][P], + resid, ReLU.
// 256 thr = 4 waves (2x2), tile 128(o) x 64(p). Cin % 128 == 0, P % 64 == 0.
// ---------------------------------------------------------------------------
template<bool B_F32, bool BF16OUT>
__global__ __launch_bounds__(256) void gemm_chunk(
    const void* __restrict__ Bsrc,
    const float* __restrict__ Wt,
    const float* __restrict__ scale,
    const float* __restrict__ shift,
    const float* __restrict__ resid,
    void* __restrict__ OutP,
    int Cin, int O, int P)
{
    const int n    = blockIdx.z;
    const int p0   = blockIdx.x * 64;
    const int o0   = blockIdx.y * 128;
    const int tid  = threadIdx.x;
    const int lane = tid & 63;
    const int wid  = tid >> 6;
    const int wm   = wid >> 1, wn = wid & 1;
    const int rl   = lane & 15;

    __shared__ short sA[128 * 128];   // [o][k] swizzled, 32 KB
    __shared__ short sB[64 * 128];    // [p][k] swizzled, 16 KB

    const int arow = tid >> 1;            // A row, 2 threads/row
    const int akh  = (tid & 1) * 64;      // A k half
    const int bp   = tid & 63;            // B row (p)
    const int bk0  = wid * 32;            // B k base (32 k per thread)

    f32x4 acc[4][2];
    #pragma unroll
    for (int i = 0; i < 4; ++i)
        #pragma unroll
        for (int j = 0; j < 2; ++j) acc[i][j] = (f32x4)0.f;

    for (int kc = 0; kc < Cin; kc += 128) {
        if (kc) __syncthreads();

        // ---- stage A: 64 k f32 -> bf16, 8 x ds_write_b128 ----
        {
            const float* wrow = Wt + (size_t)(o0 + arow) * Cin + kc + akh;
            #pragma unroll
            for (int s = 0; s < 8; ++s) {
                float4 u = *(const float4*)(wrow + s * 8);
                float4 v = *(const float4*)(wrow + s * 8 + 4);
                uint4 w = make_uint4(pk2(u.x, u.y), pk2(u.z, u.w),
                                     pk2(v.x, v.y), pk2(v.z, v.w));
                *(uint4*)(&sA[S128(arow, akh + s * 8)]) = w;
            }
        }
        // ---- stage B ----
        if constexpr (B_F32) {
            const float* bsrc = (const float*)Bsrc + (size_t)n * Cin * P
                              + (size_t)(kc + bk0) * P + (p0 + bp);
            #pragma unroll
            for (int s = 0; s < 4; ++s) {
                float f[8];
                #pragma unroll
                for (int q = 0; q < 8; ++q)
                    f[q] = bsrc[(size_t)(s * 8 + q) * P];
                uint4 w = make_uint4(pk2(f[0], f[1]), pk2(f[2], f[3]),
                                     pk2(f[4], f[5]), pk2(f[6], f[7]));
                *(uint4*)(&sB[S128(bp, bk0 + s * 8)]) = w;
            }
        } else {
            const unsigned short* brow = (const unsigned short*)Bsrc
                + ((size_t)n * P + p0 + bp) * Cin + kc + bk0;
            #pragma unroll
            for (int s = 0; s < 4; ++s) {
                uint4 w = *(const uint4*)(brow + s * 8);
                *(uint4*)(&sB[S128(bp, bk0 + s * 8)]) = w;
            }
        }
        __syncthreads();

        // ---- compute: 4 k-steps x 8 MFMA ----
        #pragma unroll
        for (int ks = 0; ks < 4; ++ks) {
            const int k0 = ks * 32 + (lane >> 4) * 8;
            bf16x8 af[4], bfr[2];
            #pragma unroll
            for (int i = 0; i < 4; ++i)
                af[i] = *(const bf16x8*)(&sA[S128(wm * 64 + i * 16 + rl, k0)]);
            #pragma unroll
            for (int j = 0; j < 2; ++j)
                bfr[j] = *(const bf16x8*)(&sB[S128(wn * 32 + j * 16 + rl, k0)]);
            #pragma unroll
            for (int i = 0; i < 4; ++i)
                #pragma unroll
                for (int j = 0; j < 2; ++j)
                    acc[i][j] = __builtin_amdgcn_mfma_f32_16x16x32_bf16(
                        af[i], bfr[j], acc[i][j], 0, 0, 0);
        }
    }

    if constexpr (BF16OUT) {
        // transpose epilogue -> bf16 [p][O], staged in sA (16 KB of it)
        __syncthreads();
        unsigned short* eL = (unsigned short*)&sA[0];   // [64 p][128 o]
        #pragma unroll
        for (int i = 0; i < 4; ++i) {
            #pragma unroll
            for (int r = 0; r < 4; ++r) {
                int ol = wm * 64 + i * 16 + (lane >> 4) * 4 + r;
                int o  = o0 + ol;
                float sc = scale[o], sh = shift[o];
                #pragma unroll
                for (int j = 0; j < 2; ++j) {
                    int p = wn * 32 + j * 16 + rl;
                    float v = fmaxf(fmaf(acc[i][j][r], sc, sh), 0.f);
                    eL[p * 128 + (ol ^ ((p & 15) << 3))] = bf16of(v);
                }
            }
        }
        __syncthreads();
        unsigned short* out = (unsigned short*)OutP;
        #pragma unroll
        for (int it = 0; it < 4; ++it) {
            int idx = tid + it * 256;          // 1024 uint4 = 64 p x 16
            int p = idx >> 4, m = idx & 15;
            uint4 u = *(const uint4*)(&eL[p * 128 + ((m ^ (p & 15)) << 3)]);
            *(uint4*)(out + ((size_t)n * P + p0 + p) * O + (m << 3)) = u;
        }
    } else {
        float* out = (float*)OutP;
        #pragma unroll
        for (int i = 0; i < 4; ++i) {
            #pragma unroll
            for (int r = 0; r < 4; ++r) {
                int o = o0 + wm * 64 + i * 16 + (lane >> 4) * 4 + r;
                float sc = scale[o], sh = shift[o];
                size_t base = ((size_t)n * O + o) * P;
                #pragma unroll
                for (int j = 0; j < 2; ++j) {
                    int p = p0 + wn * 32 + j * 16 + rl;
                    float v = fmaf(acc[i][j][r], sc, sh);
                    if (resid) v += resid[base + p];
                    out[base + p] = fmaxf(v, 0.f);
                }
            }
        }
    }
}

// ---------------------------------------------------------------------------
// res2net branch step, bf16 [p][c] I/O (round-7 verified).
// ---------------------------------------------------------------------------
__global__ __launch_bounds__(256) void gcn_step(
    const unsigned short* __restrict__ hT,
    unsigned short* __restrict__ outsT,
    const float* __restrict__ gw,
    const float* __restrict__ gb,
    const float* __restrict__ Aadj,
    const float* __restrict__ PAi,
    const float* __restrict__ bscale,
    const float* __restrict__ bshift,
    int step)
{
    const int n  = blockIdx.y;
    const int tt = blockIdx.x;
    const int tid = threadIdx.x;
    const int c  = tid & 31;
    const int tl = tid >> 5;

    __shared__ float smem[7200 + 3168 + 2100];
    float* sp  = smem;                          // [200][36]
    float* wsg = smem + 7200;                   // [96][33]
    float (*Mm)[25][28] = (float(*)[25][28])(smem + 7200 + 3168);
    unsigned short* outb = (unsigned short*)(smem + 7200);  // [200][32] alias

    const size_t rowbase = (size_t)n * 1600 + (size_t)tt * 200;
    const unsigned short* hrow = hT + rowbase * 128 + step * 32;
    const unsigned short* prow = outsT + rowbase * 128 + (step - 1) * 32;

    for (int idx = tid; idx < 800; idx += 256) {
        int p = idx >> 2, c8 = (idx & 3) << 3;
        uint4 u = *(const uint4*)(hrow + (size_t)p * 128 + c8);
        float f[8];
        unpk2(u.x, f[0], f[1]); unpk2(u.y, f[2], f[3]);
        unpk2(u.z, f[4], f[5]); unpk2(u.w, f[6], f[7]);
        if (step > 0) {
            uint4 v = *(const uint4*)(prow + (size_t)p * 128 + c8);
            float g0, g1;
            unpk2(v.x, g0, g1); f[0] += g0; f[1] += g1;
            unpk2(v.y, g0, g1); f[2] += g0; f[3] += g1;
            unpk2(v.z, g0, g1); f[4] += g0; f[5] += g1;
            unpk2(v.w, g0, g1); f[6] += g0; f[7] += g1;
        }
        float* d = sp + p * 36 + c8;
        *(float4*)d       = make_float4(f[0], f[1], f[2], f[3]);
        *(float4*)(d + 4) = make_float4(f[4], f[5], f[6], f[7]);
    }
    for (int idx = tid; idx < 96 * 32; idx += 256)
        wsg[(idx >> 5) * 33 + (idx & 31)] = gw[idx];
    for (int idx = tid; idx < 3 * 625; idx += 256) {
        int k = idx / 625, rem = idx % 625;
        Mm[k][rem / 25][rem % 25] = Aadj[idx] + PAi[idx];
    }
    __syncthreads();

    float g[3][25];
    {
        float b0 = gb[c], b1 = gb[32 + c], b2 = gb[64 + c];
        #pragma unroll
        for (int v = 0; v < 25; ++v) { g[0][v] = b0; g[1][v] = b1; g[2][v] = b2; }
    }
    const float* srow = sp + tl * 25 * 36;
    for (int cin = 0; cin < 32; ++cin) {
        float w0 = wsg[c * 33 + cin];
        float w1 = wsg[(32 + c) * 33 + cin];
        float w2 = wsg[(64 + c) * 33 + cin];
        #pragma unroll
        for (int v = 0; v < 25; ++v) {
            float sv = srow[v * 36 + cin];
            g[0][v] = fmaf(w0, sv, g[0][v]);
            g[1][v] = fmaf(w1, sv, g[1][v]);
            g[2][v] = fmaf(w2, sv, g[2][v]);
        }
    }

    float out[25];
    #pragma unroll
    for (int w = 0; w < 25; ++w) out[w] = 0.f;
    #pragma unroll
    for (int k = 0; k < 3; ++k)
        #pragma unroll
        for (int v = 0; v < 25; ++v) {
            float gv = g[k][v];
            #pragma unroll
            for (int w = 0; w < 25; ++w)
                out[w] = fmaf(gv, Mm[k][v][w], out[w]);
        }

    float sc = bscale[c], sh = bshift[c];
    __syncthreads();
    #pragma unroll
    for (int w = 0; w < 25; ++w)
        outb[(tl * 25 + w) * 32 + c] = bf16of(fmaxf(fmaf(out[w], sc, sh), 0.f));
    __syncthreads();

    unsigned short* orow = outsT + rowbase * 128 + step * 32;
    for (int idx = tid; idx < 800; idx += 256) {
        int p = idx >> 2, c8 = (idx & 3) << 3;
        uint4 u = *(const uint4*)(&outb[p * 32 + c8]);
        *(uint4*)(orow + (size_t)p * 128 + c8) = u;
    }
}

// ---------------------------------------------------------------------------
extern "C" void kernel_launch(void* const* d_in, const int* in_sizes, int n_in,
                              void* d_out, int out_size, void* d_ws, size_t ws_size,
                              hipStream_t stream)
{
    const float* x   = (const float*)d_in[0];
    const float* A   = (const float*)d_in[1];
    const float* rw  = (const float*)d_in[2];
    const float* rwb = (const float*)d_in[3];
    const float* rg  = (const float*)d_in[4];
    const float* rb  = (const float*)d_in[5];
    const float* rm  = (const float*)d_in[6];
    const float* rv  = (const float*)d_in[7];
    const float* gw  = (const float*)d_in[8];
    const float* gb  = (const float*)d_in[9];
    const float* PA  = (const float*)d_in[10];
    const float* bg  = (const float*)d_in[11];
    const float* bb  = (const float*)d_in[12];
    const float* bm  = (const float*)d_in[13];
    const float* bv  = (const float*)d_in[14];
    const float* ew  = (const float*)d_in[15];
    const float* ewb = (const float*)d_in[16];
    const float* eg  = (const float*)d_in[17];
    const float* eb  = (const float*)d_in[18];
    const float* em  = (const float*)d_in[19];
    const float* ev  = (const float*)d_in[20];

    char* wsb = (char*)d_ws;
    unsigned short* hT    = (unsigned short*)wsb;               // 26,214,400 B
    unsigned short* outsT = (unsigned short*)(wsb + 26214400);  // 26,214,400 B
    float*          prm   = (float*)(wsb + 52428800);           // 4 KB

    prep_params<<<1, 256, 0, stream>>>(rwb, rg, rb, rm, rv,
                                       ewb, eg, eb, em, ev,
                                       bg, bb, bm, bv, prm);

    // reduct: x f32 [n][256][1600] -> hT bf16 [n][1600][128]
    gemm_chunk<true, true><<<dim3(25, 1, 64), 256, 0, stream>>>(
        x, rw, prm, prm + 128, nullptr, hT, 256, 128, 1600);

    for (int i = 0; i < 4; ++i) {
        gcn_step<<<dim3(8, 64), 256, 0, stream>>>(
            hT, outsT, gw + (size_t)i * 96 * 32, gb + (size_t)i * 96,
            A, PA + (size_t)i * 3 * 625,
            prm + 768 + i * 32, prm + 896 + i * 32, i);
    }

    // expand: outsT bf16 -> d_out f32 [n][256][1600] (+x residual)
    gemm_chunk<false, false><<<dim3(25, 2, 64), 256, 0, stream>>>(
        outsT, ew, prm + 256, prm + 512, x, d_out, 128, 256, 1600);
}

// Round 9
// 209.582 us; speedup vs baseline: 1.8578x; 1.3156x over previous
//
#include <hip/hip_runtime.h>
#include <cstdint>
#include <cstddef>

#define EPSV 1e-5f

using f32x4  = __attribute__((ext_vector_type(4))) float;
using bf16x8 = __attribute__((ext_vector_type(8))) short;

// RNE pack of two f32 into two bf16 (lo -> low16, hi -> high16)
static __device__ __forceinline__ unsigned pk2(float lo, float hi) {
    unsigned a = __builtin_bit_cast(unsigned, lo);
    unsigned b = __builtin_bit_cast(unsigned, hi);
    a = (a + 0x7FFFu + ((a >> 16) & 1u)) >> 16;
    b = (b + 0x7FFFu + ((b >> 16) & 1u)) & 0xFFFF0000u;
    return a | b;
}
static __device__ __forceinline__ unsigned short bf16of(float v) {
    return (unsigned short)(pk2(v, 0.f) & 0xFFFFu);
}
static __device__ __forceinline__ void unpk2(unsigned u, float& lo, float& hi) {
    lo = __builtin_bit_cast(float, u << 16);
    hi = __builtin_bit_cast(float, u & 0xFFFF0000u);
}

// ---------------------------------------------------------------------------
__global__ __launch_bounds__(256) void prep_params(
    const float* __restrict__ rwb, const float* __restrict__ rg,
    const float* __restrict__ rb,  const float* __restrict__ rm,
    const float* __restrict__ rv,
    const float* __restrict__ ewb, const float* __restrict__ eg,
    const float* __restrict__ eb,  const float* __restrict__ em,
    const float* __restrict__ ev,
    const float* __restrict__ bg,  const float* __restrict__ bb,
    const float* __restrict__ bm,  const float* __restrict__ bv,
    float* __restrict__ prm)
{
    int t = threadIdx.x;
    if (t < 128) {
        float sc = rg[t] * rsqrtf(rv[t] + EPSV);
        prm[t]       = sc;
        prm[128 + t] = rb[t] - rm[t] * sc + rwb[t] * sc;
        float bsc = bg[t] * rsqrtf(bv[t] + EPSV);
        prm[768 + t] = bsc;
        prm[896 + t] = bb[t] - bm[t] * bsc;
    }
    {
        float sc = eg[t] * rsqrtf(ev[t] + EPSV);
        prm[256 + t] = sc;
        prm[512 + t] = eb[t] - em[t] * sc + ewb[t] * sc;
    }
}

// ---------------------------------------------------------------------------
// GEMM v2: BK=64, single-buffered 32 KB LDS, fully vectorized global access.
// A = Wt [O][Cin] f32 -> sA bf16 [128][64] XOR-swizzled.
// BMODE 0: B = f32 [NB][Cin][P]; staged via float4 row reads into rotated
//          f32 tile [64k][64p]; fragments read as 8 x b32 + pk2 pack.
// BMODE 1: B = bf16 [NB][P][Cin]; staged via uint4 into [64p][64k] swizzled.
// OUTMODE 0: f32 [NB][O][P] out; LDS-restaged epilogue, float4 resid+store.
// OUTMODE 1: bf16 [NB][P][O] out (O==128); transposed epilogue (verified).
// 256 thr = 4 waves (2x2); wave tile 64o x 32p. Cin%64==0, P%64==0.
// ---------------------------------------------------------------------------
template<int BMODE, int OUTMODE>
__global__ __launch_bounds__(256) void gemm_v2(
    const void* __restrict__ Bsrc,
    const float* __restrict__ Wt,
    const float* __restrict__ scale,
    const float* __restrict__ shift,
    const float* __restrict__ resid,
    void* __restrict__ OutP,
    int Cin, int O, int P)
{
    const int n    = blockIdx.z;
    const int p0   = blockIdx.x * 64;
    const int o0   = blockIdx.y * 128;
    const int tid  = threadIdx.x;
    const int lane = tid & 63;
    const int wid  = tid >> 6;
    const int wm   = wid >> 1, wn = wid & 1;
    const int rl   = lane & 15;

    __shared__ __align__(16) char smem[32768];
    short* sA = (short*)smem;                       // 16 KB [128][64] swz

    f32x4 acc[4][2];
    #pragma unroll
    for (int i = 0; i < 4; ++i)
        #pragma unroll
        for (int j = 0; j < 2; ++j) acc[i][j] = (f32x4)0.f;

    for (int kc = 0; kc < Cin; kc += 64) {
        if (kc) __syncthreads();

        // ---- stage A: [128 o][64 k] f32 -> bf16, float4 reads, b128 writes
        #pragma unroll
        for (int it = 0; it < 4; ++it) {
            int idx = tid + it * 256;
            int row = idx >> 3, k8 = (idx & 7) << 3;
            const float* wp = Wt + (size_t)(o0 + row) * Cin + kc + k8;
            float4 u = *(const float4*)wp;
            float4 v = *(const float4*)(wp + 4);
            uint4 w = make_uint4(pk2(u.x, u.y), pk2(u.z, u.w),
                                 pk2(v.x, v.y), pk2(v.z, v.w));
            *(uint4*)(&sA[(row << 6) + (k8 ^ ((row & 7) << 3))]) = w;
        }
        // ---- stage B ----
        if constexpr (BMODE == 0) {
            float* sBf = (float*)(smem + 16384);    // [64 k][64 p] rotated
            #pragma unroll
            for (int it = 0; it < 4; ++it) {
                int idx = tid + it * 256;
                int k = idx >> 4, p4 = (idx & 15) << 2;
                float4 u = *(const float4*)((const float*)Bsrc
                    + (size_t)n * Cin * P + (size_t)(kc + k) * P + p0 + p4);
                *(float4*)(&sBf[(k << 6) + ((p4 + (((k >> 3) & 7) << 3)) & 63)]) = u;
            }
        } else {
            short* sB = (short*)(smem + 16384);     // [64 p][64 k] swz
            #pragma unroll
            for (int it = 0; it < 2; ++it) {
                int idx = tid + it * 256;
                int p = idx >> 3, k8 = (idx & 7) << 3;
                uint4 w = *(const uint4*)((const unsigned short*)Bsrc
                    + ((size_t)n * P + p0 + p) * Cin + kc + k8);
                *(uint4*)(&sB[(p << 6) + (k8 ^ ((p & 7) << 3))]) = w;
            }
        }
        __syncthreads();

        // ---- compute: 2 k-steps x 8 MFMA ----
        #pragma unroll
        for (int ks = 0; ks < 2; ++ks) {
            const int k0 = ks * 32 + (lane >> 4) * 8;
            bf16x8 af[4], bfr[2];
            #pragma unroll
            for (int i = 0; i < 4; ++i) {
                int row = wm * 64 + i * 16 + rl;
                af[i] = *(const bf16x8*)(&sA[(row << 6) + (k0 ^ ((rl & 7) << 3))]);
            }
            if constexpr (BMODE == 0) {
                const float* sBf = (const float*)(smem + 16384);
                #pragma unroll
                for (int j = 0; j < 2; ++j) {
                    int p = wn * 32 + j * 16 + rl;
                    int base = (p + ((k0 >> 3) << 3)) & 63;
                    float f[8];
                    #pragma unroll
                    for (int q = 0; q < 8; ++q)
                        f[q] = sBf[((k0 + q) << 6) + base];
                    uint4 u = make_uint4(pk2(f[0], f[1]), pk2(f[2], f[3]),
                                         pk2(f[4], f[5]), pk2(f[6], f[7]));
                    bfr[j] = __builtin_bit_cast(bf16x8, u);
                }
            } else {
                const short* sB = (const short*)(smem + 16384);
                #pragma unroll
                for (int j = 0; j < 2; ++j) {
                    int p = wn * 32 + j * 16 + rl;
                    bfr[j] = *(const bf16x8*)(&sB[(p << 6) + (k0 ^ ((rl & 7) << 3))]);
                }
            }
            #pragma unroll
            for (int i = 0; i < 4; ++i)
                #pragma unroll
                for (int j = 0; j < 2; ++j)
                    acc[i][j] = __builtin_amdgcn_mfma_f32_16x16x32_bf16(
                        af[i], bfr[j], acc[i][j], 0, 0, 0);
        }
    }

    if constexpr (OUTMODE == 1) {
        // transposed bf16 epilogue -> [p][O] (verified r7/r8 pattern)
        __syncthreads();
        unsigned short* eL = (unsigned short*)smem;   // [64 p][128 o]
        #pragma unroll
        for (int i = 0; i < 4; ++i) {
            #pragma unroll
            for (int r = 0; r < 4; ++r) {
                int ol = wm * 64 + i * 16 + (lane >> 4) * 4 + r;
                int o  = o0 + ol;
                float sc = scale[o], sh = shift[o];
                #pragma unroll
                for (int j = 0; j < 2; ++j) {
                    int p = wn * 32 + j * 16 + rl;
                    float v = fmaxf(fmaf(acc[i][j][r], sc, sh), 0.f);
                    eL[p * 128 + (ol ^ ((p & 15) << 3))] = bf16of(v);
                }
            }
        }
        __syncthreads();
        unsigned short* out = (unsigned short*)OutP;
        #pragma unroll
        for (int it = 0; it < 4; ++it) {
            int idx = tid + it * 256;
            int p = idx >> 4, m = idx & 15;
            uint4 u = *(const uint4*)(&eL[p * 128 + ((m ^ (p & 15)) << 3)]);
            *(uint4*)(out + ((size_t)n * P + p0 + p) * O + (m << 3)) = u;
        }
    } else {
        // vectorized f32 epilogue: LDS-restage, float4 resid + store
        __syncthreads();
        float* eT = (float*)smem;                     // [128 o][64 p] rotated
        #pragma unroll
        for (int i = 0; i < 4; ++i) {
            #pragma unroll
            for (int r = 0; r < 4; ++r) {
                int ol = wm * 64 + i * 16 + (lane >> 4) * 4 + r;
                int o  = o0 + ol;
                float sc = scale[o], sh = shift[o];
                #pragma unroll
                for (int j = 0; j < 2; ++j) {
                    int p = wn * 32 + j * 16 + rl;
                    eT[(ol << 6) + ((p + ((ol & 7) << 3)) & 63)] =
                        fmaf(acc[i][j][r], sc, sh);
                }
            }
        }
        __syncthreads();
        float* out = (float*)OutP;
        #pragma unroll
        for (int it = 0; it < 8; ++it) {
            int idx = tid + it * 256;
            int ol = idx >> 4, p4 = (idx & 15) << 2;
            float4 v = *(const float4*)(&eT[(ol << 6) + ((p4 + ((ol & 7) << 3)) & 63)]);
            size_t base = ((size_t)n * O + o0 + ol) * P + p0 + p4;
            if (resid) {
                float4 r4 = *(const float4*)(resid + base);
                v.x += r4.x; v.y += r4.y; v.z += r4.z; v.w += r4.w;
            }
            v.x = fmaxf(v.x, 0.f); v.y = fmaxf(v.y, 0.f);
            v.z = fmaxf(v.z, 0.f); v.w = fmaxf(v.w, 0.f);
            *(float4*)(out + base) = v;
        }
    }
}

// ---------------------------------------------------------------------------
// res2net branch step, bf16 [p][c] I/O (verified)
// ---------------------------------------------------------------------------
__global__ __launch_bounds__(256) void gcn_step(
    const unsigned short* __restrict__ hT,
    unsigned short* __restrict__ outsT,
    const float* __restrict__ gw,
    const float* __restrict__ gb,
    const float* __restrict__ Aadj,
    const float* __restrict__ PAi,
    const float* __restrict__ bscale,
    const float* __restrict__ bshift,
    int step)
{
    const int n  = blockIdx.y;
    const int tt = blockIdx.x;
    const int tid = threadIdx.x;
    const int c  = tid & 31;
    const int tl = tid >> 5;

    __shared__ float smem[7200 + 3168 + 2100];
    float* sp  = smem;                          // [200][36]
    float* wsg = smem + 7200;                   // [96][33]
    float (*Mm)[25][28] = (float(*)[25][28])(smem + 7200 + 3168);
    unsigned short* outb = (unsigned short*)(smem + 7200);  // [200][32] alias

    const size_t rowbase = (size_t)n * 1600 + (size_t)tt * 200;
    const unsigned short* hrow = hT + rowbase * 128 + step * 32;
    const unsigned short* prow = outsT + rowbase * 128 + (step - 1) * 32;

    for (int idx = tid; idx < 800; idx += 256) {
        int p = idx >> 2, c8 = (idx & 3) << 3;
        uint4 u = *(const uint4*)(hrow + (size_t)p * 128 + c8);
        float f[8];
        unpk2(u.x, f[0], f[1]); unpk2(u.y, f[2], f[3]);
        unpk2(u.z, f[4], f[5]); unpk2(u.w, f[6], f[7]);
        if (step > 0) {
            uint4 v = *(const uint4*)(prow + (size_t)p * 128 + c8);
            float g0, g1;
            unpk2(v.x, g0, g1); f[0] += g0; f[1] += g1;
            unpk2(v.y, g0, g1); f[2] += g0; f[3] += g1;
            unpk2(v.z, g0, g1); f[4] += g0; f[5] += g1;
            unpk2(v.w, g0, g1); f[6] += g0; f[7] += g1;
        }
        float* d = sp + p * 36 + c8;
        *(float4*)d       = make_float4(f[0], f[1], f[2], f[3]);
        *(float4*)(d + 4) = make_float4(f[4], f[5], f[6], f[7]);
    }
    for (int idx = tid; idx < 96 * 32; idx += 256)
        wsg[(idx >> 5) * 33 + (idx & 31)] = gw[idx];
    for (int idx = tid; idx < 3 * 625; idx += 256) {
        int k = idx / 625, rem = idx % 625;
        Mm[k][rem / 25][rem % 25] = Aadj[idx] + PAi[idx];
    }
    __syncthreads();

    float g[3][25];
    {
        float b0 = gb[c], b1 = gb[32 + c], b2 = gb[64 + c];
        #pragma unroll
        for (int v = 0; v < 25; ++v) { g[0][v] = b0; g[1][v] = b1; g[2][v] = b2; }
    }
    const float* srow = sp + tl * 25 * 36;
    for (int cin = 0; cin < 32; ++cin) {
        float w0 = wsg[c * 33 + cin];
        float w1 = wsg[(32 + c) * 33 + cin];
        float w2 = wsg[(64 + c) * 33 + cin];
        #pragma unroll
        for (int v = 0; v < 25; ++v) {
            float sv = srow[v * 36 + cin];
            g[0][v] = fmaf(w0, sv, g[0][v]);
            g[1][v] = fmaf(w1, sv, g[1][v]);
            g[2][v] = fmaf(w2, sv, g[2][v]);
        }
    }

    float out[25];
    #pragma unroll
    for (int w = 0; w < 25; ++w) out[w] = 0.f;
    #pragma unroll
    for (int k = 0; k < 3; ++k)
        #pragma unroll
        for (int v = 0; v < 25; ++v) {
            float gv = g[k][v];
            #pragma unroll
            for (int w = 0; w < 25; ++w)
                out[w] = fmaf(gv, Mm[k][v][w], out[w]);
        }

    float sc = bscale[c], sh = bshift[c];
    __syncthreads();
    #pragma unroll
    for (int w = 0; w < 25; ++w)
        outb[(tl * 25 + w) * 32 + c] = bf16of(fmaxf(fmaf(out[w], sc, sh), 0.f));
    __syncthreads();

    unsigned short* orow = outsT + rowbase * 128 + step * 32;
    for (int idx = tid; idx < 800; idx += 256) {
        int p = idx >> 2, c8 = (idx & 3) << 3;
        uint4 u = *(const uint4*)(&outb[p * 32 + c8]);
        *(uint4*)(orow + (size_t)p * 128 + c8) = u;
    }
}

// ---------------------------------------------------------------------------
extern "C" void kernel_launch(void* const* d_in, const int* in_sizes, int n_in,
                              void* d_out, int out_size, void* d_ws, size_t ws_size,
                              hipStream_t stream)
{
    const float* x   = (const float*)d_in[0];
    const float* A   = (const float*)d_in[1];
    const float* rw  = (const float*)d_in[2];
    const float* rwb = (const float*)d_in[3];
    const float* rg  = (const float*)d_in[4];
    const float* rb  = (const float*)d_in[5];
    const float* rm  = (const float*)d_in[6];
    const float* rv  = (const float*)d_in[7];
    const float* gw  = (const float*)d_in[8];
    const float* gb  = (const float*)d_in[9];
    const float* PA  = (const float*)d_in[10];
    const float* bg  = (const float*)d_in[11];
    const float* bb  = (const float*)d_in[12];
    const float* bm  = (const float*)d_in[13];
    const float* bv  = (const float*)d_in[14];
    const float* ew  = (const float*)d_in[15];
    const float* ewb = (const float*)d_in[16];
    const float* eg  = (const float*)d_in[17];
    const float* eb  = (const float*)d_in[18];
    const float* em  = (const float*)d_in[19];
    const float* ev  = (const float*)d_in[20];

    char* wsb = (char*)d_ws;
    unsigned short* hT    = (unsigned short*)wsb;               // 26,214,400 B
    unsigned short* outsT = (unsigned short*)(wsb + 26214400);  // 26,214,400 B
    float*          prm   = (float*)(wsb + 52428800);           // 4 KB

    prep_params<<<1, 256, 0, stream>>>(rwb, rg, rb, rm, rv,
                                       ewb, eg, eb, em, ev,
                                       bg, bb, bm, bv, prm);

    // reduct: x f32 [n][256][1600] -> hT bf16 [n][1600][128]
    gemm_v2<0, 1><<<dim3(25, 1, 64), 256, 0, stream>>>(
        x, rw, prm, prm + 128, nullptr, hT, 256, 128, 1600);

    for (int i = 0; i < 4; ++i) {
        gcn_step<<<dim3(8, 64), 256, 0, stream>>>(
            hT, outsT, gw + (size_t)i * 96 * 32, gb + (size_t)i * 96,
            A, PA + (size_t)i * 3 * 625,
            prm + 768 + i * 32, prm + 896 + i * 32, i);
    }

    // expand: outsT bf16 -> d_out f32 [n][256][1600] (+x residual)
    gemm_v2<1, 0><<<dim3(25, 2, 64), 256, 0, stream>>>(
        outsT, ew, prm + 256, prm + 512, x, d_out, 128, 256, 1600);
}

// Round 10
// 187.666 us; speedup vs baseline: 2.0747x; 1.1168x over previous
//
#include <hip/hip_runtime.h>
#include <cstdint>
#include <cstddef>

#define EPSV 1e-5f

using f32x4  = __attribute__((ext_vector_type(4))) float;
using bf16x8 = __attribute__((ext_vector_type(8))) short;

// RNE pack of two f32 into two bf16 (lo -> low16, hi -> high16)
static __device__ __forceinline__ unsigned pk2(float lo, float hi) {
    unsigned a = __builtin_bit_cast(unsigned, lo);
    unsigned b = __builtin_bit_cast(unsigned, hi);
    a = (a + 0x7FFFu + ((a >> 16) & 1u)) >> 16;
    b = (b + 0x7FFFu + ((b >> 16) & 1u)) & 0xFFFF0000u;
    return a | b;
}
static __device__ __forceinline__ unsigned short bf16of(float v) {
    return (unsigned short)(pk2(v, 0.f) & 0xFFFFu);
}
static __device__ __forceinline__ void unpk2(unsigned u, float& lo, float& hi) {
    lo = __builtin_bit_cast(float, u << 16);
    hi = __builtin_bit_cast(float, u & 0xFFFF0000u);
}

// ---------------------------------------------------------------------------
__global__ __launch_bounds__(256) void prep_params(
    const float* __restrict__ rwb, const float* __restrict__ rg,
    const float* __restrict__ rb,  const float* __restrict__ rm,
    const float* __restrict__ rv,
    const float* __restrict__ ewb, const float* __restrict__ eg,
    const float* __restrict__ eb,  const float* __restrict__ em,
    const float* __restrict__ ev,
    const float* __restrict__ bg,  const float* __restrict__ bb,
    const float* __restrict__ bm,  const float* __restrict__ bv,
    float* __restrict__ prm)
{
    int t = threadIdx.x;
    if (t < 128) {
        float sc = rg[t] * rsqrtf(rv[t] + EPSV);
        prm[t]       = sc;
        prm[128 + t] = rb[t] - rm[t] * sc + rwb[t] * sc;
        float bsc = bg[t] * rsqrtf(bv[t] + EPSV);
        prm[768 + t] = bsc;
        prm[896 + t] = bb[t] - bm[t] * bsc;
    }
    {
        float sc = eg[t] * rsqrtf(ev[t] + EPSV);
        prm[256 + t] = sc;
        prm[512 + t] = eb[t] - em[t] * sc + ewb[t] * sc;
    }
}

// ---------------------------------------------------------------------------
// GEMM v2 (round-9 verified, unchanged): BK=64, 32 KB LDS, vectorized I/O.
// ---------------------------------------------------------------------------
template<int BMODE, int OUTMODE>
__global__ __launch_bounds__(256) void gemm_v2(
    const void* __restrict__ Bsrc,
    const float* __restrict__ Wt,
    const float* __restrict__ scale,
    const float* __restrict__ shift,
    const float* __restrict__ resid,
    void* __restrict__ OutP,
    int Cin, int O, int P)
{
    const int n    = blockIdx.z;
    const int p0   = blockIdx.x * 64;
    const int o0   = blockIdx.y * 128;
    const int tid  = threadIdx.x;
    const int lane = tid & 63;
    const int wid  = tid >> 6;
    const int wm   = wid >> 1, wn = wid & 1;
    const int rl   = lane & 15;

    __shared__ __align__(16) char smem[32768];
    short* sA = (short*)smem;                       // 16 KB [128][64] swz

    f32x4 acc[4][2];
    #pragma unroll
    for (int i = 0; i < 4; ++i)
        #pragma unroll
        for (int j = 0; j < 2; ++j) acc[i][j] = (f32x4)0.f;

    for (int kc = 0; kc < Cin; kc += 64) {
        if (kc) __syncthreads();

        #pragma unroll
        for (int it = 0; it < 4; ++it) {
            int idx = tid + it * 256;
            int row = idx >> 3, k8 = (idx & 7) << 3;
            const float* wp = Wt + (size_t)(o0 + row) * Cin + kc + k8;
            float4 u = *(const float4*)wp;
            float4 v = *(const float4*)(wp + 4);
            uint4 w = make_uint4(pk2(u.x, u.y), pk2(u.z, u.w),
                                 pk2(v.x, v.y), pk2(v.z, v.w));
            *(uint4*)(&sA[(row << 6) + (k8 ^ ((row & 7) << 3))]) = w;
        }
        if constexpr (BMODE == 0) {
            float* sBf = (float*)(smem + 16384);    // [64 k][64 p] rotated
            #pragma unroll
            for (int it = 0; it < 4; ++it) {
                int idx = tid + it * 256;
                int k = idx >> 4, p4 = (idx & 15) << 2;
                float4 u = *(const float4*)((const float*)Bsrc
                    + (size_t)n * Cin * P + (size_t)(kc + k) * P + p0 + p4);
                *(float4*)(&sBf[(k << 6) + ((p4 + (((k >> 3) & 7) << 3)) & 63)]) = u;
            }
        } else {
            short* sB = (short*)(smem + 16384);     // [64 p][64 k] swz
            #pragma unroll
            for (int it = 0; it < 2; ++it) {
                int idx = tid + it * 256;
                int p = idx >> 3, k8 = (idx & 7) << 3;
                uint4 w = *(const uint4*)((const unsigned short*)Bsrc
                    + ((size_t)n * P + p0 + p) * Cin + kc + k8);
                *(uint4*)(&sB[(p << 6) + (k8 ^ ((p & 7) << 3))]) = w;
            }
        }
        __syncthreads();

        #pragma unroll
        for (int ks = 0; ks < 2; ++ks) {
            const int k0 = ks * 32 + (lane >> 4) * 8;
            bf16x8 af[4], bfr[2];
            #pragma unroll
            for (int i = 0; i < 4; ++i) {
                int row = wm * 64 + i * 16 + rl;
                af[i] = *(const bf16x8*)(&sA[(row << 6) + (k0 ^ ((rl & 7) << 3))]);
            }
            if constexpr (BMODE == 0) {
                const float* sBf = (const float*)(smem + 16384);
                #pragma unroll
                for (int j = 0; j < 2; ++j) {
                    int p = wn * 32 + j * 16 + rl;
                    int base = (p + ((k0 >> 3) << 3)) & 63;
                    float f[8];
                    #pragma unroll
                    for (int q = 0; q < 8; ++q)
                        f[q] = sBf[((k0 + q) << 6) + base];
                    uint4 u = make_uint4(pk2(f[0], f[1]), pk2(f[2], f[3]),
                                         pk2(f[4], f[5]), pk2(f[6], f[7]));
                    bfr[j] = __builtin_bit_cast(bf16x8, u);
                }
            } else {
                const short* sB = (const short*)(smem + 16384);
                #pragma unroll
                for (int j = 0; j < 2; ++j) {
                    int p = wn * 32 + j * 16 + rl;
                    bfr[j] = *(const bf16x8*)(&sB[(p << 6) + (k0 ^ ((rl & 7) << 3))]);
                }
            }
            #pragma unroll
            for (int i = 0; i < 4; ++i)
                #pragma unroll
                for (int j = 0; j < 2; ++j)
                    acc[i][j] = __builtin_amdgcn_mfma_f32_16x16x32_bf16(
                        af[i], bfr[j], acc[i][j], 0, 0, 0);
        }
    }

    if constexpr (OUTMODE == 1) {
        __syncthreads();
        unsigned short* eL = (unsigned short*)smem;   // [64 p][128 o]
        #pragma unroll
        for (int i = 0; i < 4; ++i) {
            #pragma unroll
            for (int r = 0; r < 4; ++r) {
                int ol = wm * 64 + i * 16 + (lane >> 4) * 4 + r;
                int o  = o0 + ol;
                float sc = scale[o], sh = shift[o];
                #pragma unroll
                for (int j = 0; j < 2; ++j) {
                    int p = wn * 32 + j * 16 + rl;
                    float v = fmaxf(fmaf(acc[i][j][r], sc, sh), 0.f);
                    eL[p * 128 + (ol ^ ((p & 15) << 3))] = bf16of(v);
                }
            }
        }
        __syncthreads();
        unsigned short* out = (unsigned short*)OutP;
        #pragma unroll
        for (int it = 0; it < 4; ++it) {
            int idx = tid + it * 256;
            int p = idx >> 4, m = idx & 15;
            uint4 u = *(const uint4*)(&eL[p * 128 + ((m ^ (p & 15)) << 3)]);
            *(uint4*)(out + ((size_t)n * P + p0 + p) * O + (m << 3)) = u;
        }
    } else {
        __syncthreads();
        float* eT = (float*)smem;                     // [128 o][64 p] rotated
        #pragma unroll
        for (int i = 0; i < 4; ++i) {
            #pragma unroll
            for (int r = 0; r < 4; ++r) {
                int ol = wm * 64 + i * 16 + (lane >> 4) * 4 + r;
                int o  = o0 + ol;
                float sc = scale[o], sh = shift[o];
                #pragma unroll
                for (int j = 0; j < 2; ++j) {
                    int p = wn * 32 + j * 16 + rl;
                    eT[(ol << 6) + ((p + ((ol & 7) << 3)) & 63)] =
                        fmaf(acc[i][j][r], sc, sh);
                }
            }
        }
        __syncthreads();
        float* out = (float*)OutP;
        #pragma unroll
        for (int it = 0; it < 8; ++it) {
            int idx = tid + it * 256;
            int ol = idx >> 4, p4 = (idx & 15) << 2;
            float4 v = *(const float4*)(&eT[(ol << 6) + ((p4 + ((ol & 7) << 3)) & 63)]);
            size_t base = ((size_t)n * O + o0 + ol) * P + p0 + p4;
            if (resid) {
                float4 r4 = *(const float4*)(resid + base);
                v.x += r4.x; v.y += r4.y; v.z += r4.z; v.w += r4.w;
            }
            v.x = fmaxf(v.x, 0.f); v.y = fmaxf(v.y, 0.f);
            v.z = fmaxf(v.z, 0.f); v.w = fmaxf(v.w, 0.f);
            *(float4*)(out + base) = v;
        }
    }
}

// ---------------------------------------------------------------------------
// Fused res2net chain: all 4 steps in one block per (n, t-tile).
// hT/outsT: [64][1600][128] bf16. sp state stays f32 in LDS across steps.
// 256 thr: thread owns (c = tid&31, tl = tid>>5); 200 p = 8 tl x 25 v.
// ---------------------------------------------------------------------------
__global__ __launch_bounds__(256) void gcn_fused(
    const unsigned short* __restrict__ hT,
    unsigned short* __restrict__ outsT,
    const float* __restrict__ gw,     // [4][96][32]
    const float* __restrict__ gb,     // [4][96]
    const float* __restrict__ Aadj,   // [3][25][25]
    const float* __restrict__ PA,     // [4][3][25][25]
    const float* __restrict__ bsc4,   // [4][32]
    const float* __restrict__ bsh4)   // [4][32]
{
    const int n  = blockIdx.y;
    const int tt = blockIdx.x;
    const int tid = threadIdx.x;
    const int c  = tid & 31;
    const int tl = tid >> 5;

    __shared__ float sp[200 * 36];              // 28.8 KB, f32 state
    __shared__ float wsg[96 * 33];              // 12.7 KB
    __shared__ float Mm[3][25][28];             // 8.4 KB
    __shared__ unsigned short outb[200 * 32];   // 12.8 KB

    const size_t rowbase = (size_t)n * 1600 + (size_t)tt * 200;

    // ---- init: sp = h chunk 0 (f32), stage step-0 weights ----
    {
        const unsigned short* hrow = hT + rowbase * 128;
        for (int idx = tid; idx < 800; idx += 256) {
            int p = idx >> 2, c8 = (idx & 3) << 3;
            uint4 u = *(const uint4*)(hrow + (size_t)p * 128 + c8);
            float f[8];
            unpk2(u.x, f[0], f[1]); unpk2(u.y, f[2], f[3]);
            unpk2(u.z, f[4], f[5]); unpk2(u.w, f[6], f[7]);
            float* d = sp + p * 36 + c8;
            *(float4*)d       = make_float4(f[0], f[1], f[2], f[3]);
            *(float4*)(d + 4) = make_float4(f[4], f[5], f[6], f[7]);
        }
        for (int idx = tid; idx < 96 * 32; idx += 256)
            wsg[(idx >> 5) * 33 + (idx & 31)] = gw[idx];
        for (int idx = tid; idx < 3 * 625; idx += 256) {
            int k = idx / 625, rem = idx % 625;
            Mm[k][rem / 25][rem % 25] = Aadj[idx] + PA[idx];
        }
    }
    __syncthreads();

    for (int step = 0; step < 4; ++step) {
        // ---- conv 32->96 (sp reads broadcast over 32-lane groups) ----
        float g[3][25];
        {
            const float* gbp = gb + step * 96;
            float b0 = gbp[c], b1 = gbp[32 + c], b2 = gbp[64 + c];
            #pragma unroll
            for (int v = 0; v < 25; ++v) { g[0][v] = b0; g[1][v] = b1; g[2][v] = b2; }
        }
        const float* srow = sp + tl * 25 * 36;
        for (int cin = 0; cin < 32; ++cin) {
            float w0 = wsg[c * 33 + cin];
            float w1 = wsg[(32 + c) * 33 + cin];
            float w2 = wsg[(64 + c) * 33 + cin];
            #pragma unroll
            for (int v = 0; v < 25; ++v) {
                float sv = srow[v * 36 + cin];
                g[0][v] = fmaf(w0, sv, g[0][v]);
                g[1][v] = fmaf(w1, sv, g[1][v]);
                g[2][v] = fmaf(w2, sv, g[2][v]);
            }
        }

        // ---- adjacency mix ----
        float out[25];
        #pragma unroll
        for (int w = 0; w < 25; ++w) out[w] = 0.f;
        #pragma unroll
        for (int k = 0; k < 3; ++k)
            #pragma unroll
            for (int v = 0; v < 25; ++v) {
                float gv = g[k][v];
                #pragma unroll
                for (int w = 0; w < 25; ++w)
                    out[w] = fmaf(gv, Mm[k][v][w], out[w]);
            }

        // ---- BN + ReLU ----
        float sc = bsc4[step * 32 + c], sh = bsh4[step * 32 + c];
        #pragma unroll
        for (int w = 0; w < 25; ++w)
            out[w] = fmaxf(fmaf(out[w], sc, sh), 0.f);

        __syncthreads();   // all conv/mix reads of sp, wsg, Mm complete

        // ---- write new sp (f32, next step's input) + bf16 outb ----
        #pragma unroll
        for (int w = 0; w < 25; ++w) {
            sp[(tl * 25 + w) * 36 + c] = out[w];
            outb[(tl * 25 + w) * 32 + c] = bf16of(out[w]);
        }
        __syncthreads();   // sp/outb writes complete

        // ---- store outb -> outsT chunk `step` (coalesced uint4) ----
        {
            unsigned short* orow = outsT + rowbase * 128 + step * 32;
            for (int idx = tid; idx < 800; idx += 256) {
                int p = idx >> 2, c8 = (idx & 3) << 3;
                uint4 u = *(const uint4*)(&outb[p * 32 + c8]);
                *(uint4*)(orow + (size_t)p * 128 + c8) = u;
            }
        }

        if (step < 3) {
            // ---- sp += h chunk step+1 ; stage next weights ----
            const unsigned short* hrow = hT + rowbase * 128 + (step + 1) * 32;
            for (int idx = tid; idx < 800; idx += 256) {
                int p = idx >> 2, c8 = (idx & 3) << 3;
                uint4 u = *(const uint4*)(hrow + (size_t)p * 128 + c8);
                float f[8];
                unpk2(u.x, f[0], f[1]); unpk2(u.y, f[2], f[3]);
                unpk2(u.z, f[4], f[5]); unpk2(u.w, f[6], f[7]);
                float* d = sp + p * 36 + c8;
                #pragma unroll
                for (int q = 0; q < 8; ++q) d[q] += f[q];
            }
            const float* gwp = gw + (step + 1) * 96 * 32;
            for (int idx = tid; idx < 96 * 32; idx += 256)
                wsg[(idx >> 5) * 33 + (idx & 31)] = gwp[idx];
            const float* pap = PA + (step + 1) * 3 * 625;
            for (int idx = tid; idx < 3 * 625; idx += 256) {
                int k = idx / 625, rem = idx % 625;
                Mm[k][rem / 25][rem % 25] = Aadj[idx] + pap[idx];
            }
            __syncthreads();   // sp/wsg/Mm ready for next conv
        }
    }
}

// ---------------------------------------------------------------------------
extern "C" void kernel_launch(void* const* d_in, const int* in_sizes, int n_in,
                              void* d_out, int out_size, void* d_ws, size_t ws_size,
                              hipStream_t stream)
{
    const float* x   = (const float*)d_in[0];
    const float* A   = (const float*)d_in[1];
    const float* rw  = (const float*)d_in[2];
    const float* rwb = (const float*)d_in[3];
    const float* rg  = (const float*)d_in[4];
    const float* rb  = (const float*)d_in[5];
    const float* rm  = (const float*)d_in[6];
    const float* rv  = (const float*)d_in[7];
    const float* gw  = (const float*)d_in[8];
    const float* gb  = (const float*)d_in[9];
    const float* PA  = (const float*)d_in[10];
    const float* bg  = (const float*)d_in[11];
    const float* bb  = (const float*)d_in[12];
    const float* bm  = (const float*)d_in[13];
    const float* bv  = (const float*)d_in[14];
    const float* ew  = (const float*)d_in[15];
    const float* ewb = (const float*)d_in[16];
    const float* eg  = (const float*)d_in[17];
    const float* eb  = (const float*)d_in[18];
    const float* em  = (const float*)d_in[19];
    const float* ev  = (const float*)d_in[20];

    char* wsb = (char*)d_ws;
    unsigned short* hT    = (unsigned short*)wsb;               // 26,214,400 B
    unsigned short* outsT = (unsigned short*)(wsb + 26214400);  // 26,214,400 B
    float*          prm   = (float*)(wsb + 52428800);           // 4 KB

    prep_params<<<1, 256, 0, stream>>>(rwb, rg, rb, rm, rv,
                                       ewb, eg, eb, em, ev,
                                       bg, bb, bm, bv, prm);

    // reduct: x f32 [n][256][1600] -> hT bf16 [n][1600][128]
    gemm_v2<0, 1><<<dim3(25, 1, 64), 256, 0, stream>>>(
        x, rw, prm, prm + 128, nullptr, hT, 256, 128, 1600);

    // fused res2net chain (4 steps in one launch)
    gcn_fused<<<dim3(8, 64), 256, 0, stream>>>(
        hT, outsT, gw, gb, A, PA, prm + 768, prm + 896);

    // expand: outsT bf16 -> d_out f32 [n][256][1600] (+x residual)
    gemm_v2<1, 0><<<dim3(25, 2, 64), 256, 0, stream>>>(
        outsT, ew, prm + 256, prm + 512, x, d_out, 128, 256, 1600);
}